// Round 4
// baseline (419.059 us; speedup 1.0000x reference)
//
#include <hip/hip_runtime.h>

// Causal linear attention (chunked scan), bf16 MFMA end-to-end.
// q = softmax(x Wq^T), k = softmax(x Wk^T), v = x Wv^T   (one fused MFMA GEMM)
// fused_tail (single launch, manual device-scope grid barrier):
//   phase1: T_c = sum_t v_t^T (x) k_t   (MFMA)
//   phase2: exclusive prefix of T_c over chunks (fp32 scan -> bf16)
//   phase3: out = Q @ Tpre^T + tril(Q K^T) @ V   (MFMA)

constexpr int DIM  = 1024;
constexpr int H    = 16;
constexpr int DH   = 64;
constexpr int LSEQ = 2048;
constexpr int NB   = 2;
constexpr int MTOK = NB * LSEQ;   // 4096 tokens
constexpr int CS   = 64;          // chunk size
constexpr int NC   = LSEQ / CS;   // 32 chunks
constexpr int NTILE = NC * H * NB; // 1024 (c,h,n) tiles
constexpr int TGRID = 768;         // 3 blocks/CU x 256 CUs -- all co-resident

typedef __bf16 bf16x8 __attribute__((ext_vector_type(8)));
typedef float floatx4 __attribute__((ext_vector_type(4)));
typedef unsigned short ushort_t;

__device__ __forceinline__ ushort_t f2bf(float f) {
  unsigned int u = __float_as_uint(f);
  u += 0x7FFFu + ((u >> 16) & 1u);   // RTNE
  return (ushort_t)(u >> 16);
}

__device__ __forceinline__ void async16(void* lds, const void* g) {
  __builtin_amdgcn_global_load_lds(
      (const __attribute__((address_space(1))) unsigned int*)g,
      (__attribute__((address_space(3))) unsigned int*)lds, 16, 0, 0);
}

// read a bf16x8 fragment from a transposed stride-33-uint LDS array
__device__ __forceinline__ bf16x8 tfrag(const unsigned int* T, int row, int uoff) {
  union { bf16x8 v; unsigned int u[4]; } r;
  const unsigned int* p = T + row * 33 + uoff;
  r.u[0] = p[0]; r.u[1] = p[1]; r.u[2] = p[2]; r.u[3] = p[3];
  return r.v;
}

// transpose a 64x64 bf16 tile (global, row stride DIM) into stride-33-uint LDS
__device__ __forceinline__ void transpose_tile(const ushort_t* g, unsigned int* TT, int tid) {
  const int ic = tid & 7, tp = tid >> 3;       // tp 0..31, ic 0..7
  const ushort_t* r0 = g + (size_t)(2 * tp) * DIM + ic * 8;
  union { uint4 q; ushort_t u[8]; } a0, a1;
  a0.q = *(const uint4*)r0;
  a1.q = *(const uint4*)(r0 + DIM);
#pragma unroll
  for (int j = 0; j < 8; j++)
    TT[(8 * ic + j) * 33 + tp] = (unsigned int)a0.u[j] | ((unsigned int)a1.u[j] << 16);
}

// ---- manual grid barrier (device-scope, sense-reversing w/ generation) -----
// Safe because all TGRID blocks are co-resident (exact-capacity launch).
// Self-restoring across graph replays: bar returns to 0, gen is monotonic.
__device__ int g_bar = 0;
__device__ int g_gen = 0;

__device__ __forceinline__ void grid_sync_all() {
  __syncthreads();
  if (threadIdx.x == 0) {
    __threadfence();   // release: make this block's global writes visible
    const int g = __hip_atomic_load(&g_gen, __ATOMIC_RELAXED, __HIP_MEMORY_SCOPE_AGENT);
    if (__hip_atomic_fetch_add(&g_bar, 1, __ATOMIC_ACQ_REL, __HIP_MEMORY_SCOPE_AGENT)
        == TGRID - 1) {
      // reset BEFORE releasing gen so next-phase arrivals can't be clobbered
      __hip_atomic_store(&g_bar, 0, __ATOMIC_RELAXED, __HIP_MEMORY_SCOPE_AGENT);
      __hip_atomic_fetch_add(&g_gen, 1, __ATOMIC_RELEASE, __HIP_MEMORY_SCOPE_AGENT);
    } else {
      while (__hip_atomic_load(&g_gen, __ATOMIC_ACQUIRE, __HIP_MEMORY_SCOPE_AGENT) == g)
        __builtin_amdgcn_s_sleep(1);
    }
    __threadfence();   // acquire side: invalidate L1 before plain reads
  }
  __syncthreads();
}

// ------------- cast fp32 -> bf16 for query/key and the three weights --------
__global__ __launch_bounds__(256) void cast_all(const float* __restrict__ q,
                                                const float* __restrict__ k,
                                                const float* __restrict__ wq,
                                                const float* __restrict__ wk,
                                                const float* __restrict__ wv,
                                                ushort_t* __restrict__ xbf,
                                                ushort_t* __restrict__ wbf) {
  const int seg = blockIdx.y;
  const float* src;
  ushort_t* dst;
  int n4;
  if (seg == 0)      { src = q;  dst = xbf;                  n4 = (4 << 20) / 4; }
  else if (seg == 1) { src = k;  dst = xbf + (4 << 20);      n4 = (4 << 20) / 4; }
  else if (seg == 2) { src = wq; dst = wbf;                  n4 = (1 << 20) / 4; }
  else if (seg == 3) { src = wk; dst = wbf + (1 << 20);      n4 = (1 << 20) / 4; }
  else               { src = wv; dst = wbf + (2 << 20);      n4 = (1 << 20) / 4; }
  for (int i = blockIdx.x * 256 + threadIdx.x; i < n4; i += gridDim.x * 256) {
    const float4 f = ((const float4*)src)[i];
    ((ushort4*)dst)[i] = make_ushort4(f2bf(f.x), f2bf(f.y), f2bf(f.z), f2bf(f.w));
  }
}

// ----- fused bf16 MFMA GEMM NT: z in {0:q,1:k,2:v}, tile 128x128, BK=32 -----
// 4 waves in 2x2; each wave 64x64 (4x4 MFMA / K-iter). In-register per-head
// softmax epilogue for z<2 (wave's 64 cols == one head).
// 3-stage LDS pipeline, counted vmcnt(4) + raw s_barrier.
// XCD-aware swizzle (T1): HW round-robins blockIdx across the 8 XCDs; remap
// so XCD x owns bm-panels [4x,4x+4) for ALL z (z1/z2 share the key-x A rows),
// bn fastest.
struct Stage { ushort_t As[128 * 32]; ushort_t Ws[128 * 32]; };
union SMemU { Stage st[3]; ushort_t CsB[128 * 136]; };

__global__ __launch_bounds__(256) void gemm_fused(const ushort_t* __restrict__ xbf,
                                                  const ushort_t* __restrict__ wbf,
                                                  ushort_t* __restrict__ qp,
                                                  ushort_t* __restrict__ kp,
                                                  ushort_t* __restrict__ vp) {
  __shared__ SMemU sm;
  const int tid  = threadIdx.x;

  // swizzled decode: flat 0..767; XCD = flat&7; local 0..95 within XCD
  const int flat  = blockIdx.x;
  const int xcd   = flat & 7;
  const int local = flat >> 3;          // 0..95
  const int z     = local >> 5;         // 0..2
  const int l2    = local & 31;
  const int bn    = (l2 & 7) * 128;
  const int bm    = (xcd * 4 + (l2 >> 3)) * 128;

  const ushort_t* A = xbf + (z ? (size_t)(4 << 20) : 0);
  const ushort_t* W = wbf + (size_t)z * (1 << 20);
  ushort_t* C = (z == 0) ? qp : ((z == 1) ? kp : vp);
  const int lane = tid & 63;
  const int wid  = tid >> 6;
  const int wm   = wid >> 1, wn = wid & 1;
  const int row16 = lane & 15, quad = lane >> 4;

  floatx4 acc[4][4] = {};

  const int srow = tid >> 2;                               // 0..63
  const int cg   = (tid & 3) ^ ((srow ^ (srow >> 2)) & 3); // swizzled src chunk
  const ushort_t* gA0 = A + (size_t)(bm + srow) * DIM + cg * 8;
  const ushort_t* gA1 = A + (size_t)(bm + 64 + srow) * DIM + cg * 8;
  const ushort_t* gW0 = W + (size_t)(bn + srow) * DIM + cg * 8;
  const ushort_t* gW1 = W + (size_t)(bn + 64 + srow) * DIM + cg * 8;

#define STAGE(buf, koff)                                    \
  {                                                         \
    Stage& s_ = sm.st[buf];                                 \
    async16(s_.As + tid * 8,         gA0 + (koff));         \
    async16(s_.As + (tid + 256) * 8, gA1 + (koff));         \
    async16(s_.Ws + tid * 8,         gW0 + (koff));         \
    async16(s_.Ws + (tid + 256) * 8, gW1 + (koff));         \
  }

  // reader-side swizzled chunk (per-thread constant; matches source permute)
  const int qx   = quad ^ ((row16 ^ (row16 >> 2)) & 3);
  const int aoff = (wm * 64 + row16) * 32 + qx * 8;   // + mt*512
  const int boff = (wn * 64 + row16) * 32 + qx * 8;   // + nt*512

  // prologue: stage K-slabs 0 and 1 into buffers 0 and 1 (8 loads in flight)
  STAGE(0, 0);
  STAGE(1, 32);

  int cur = 0, pf = 2;
  for (int s = 0; s < 32; ++s) {
    if (s < 31) asm volatile("s_waitcnt vmcnt(4)" ::: "memory");
    else        asm volatile("s_waitcnt vmcnt(0)" ::: "memory");
    __builtin_amdgcn_s_barrier();
    if (s + 2 < 32) STAGE(pf, (s + 2) * 32);

    const Stage& st = sm.st[cur];
    bf16x8 a[4], b[4];
#pragma unroll
    for (int mt = 0; mt < 4; mt++)
      a[mt] = *(const bf16x8*)&st.As[aoff + mt * 512];
#pragma unroll
    for (int nt = 0; nt < 4; nt++)
      b[nt] = *(const bf16x8*)&st.Ws[boff + nt * 512];
#pragma unroll
    for (int mt = 0; mt < 4; mt++)
#pragma unroll
      for (int nt = 0; nt < 4; nt++)
        acc[mt][nt] = __builtin_amdgcn_mfma_f32_16x16x32_bf16(a[mt], b[nt], acc[mt][nt], 0, 0, 0);

    cur = (cur == 2) ? 0 : cur + 1;
    pf  = (pf  == 2) ? 0 : pf + 1;
  }
#undef STAGE
  __syncthreads();   // all ds_reads done before LDS reuse as CsB

  if (z < 2) {
    // in-register per-head softmax: row (mt,quad,r) spans nt regs x 16 lanes
#pragma unroll
    for (int mt = 0; mt < 4; mt++)
#pragma unroll
      for (int r = 0; r < 4; r++) {
        float m = fmaxf(fmaxf(acc[mt][0][r], acc[mt][1][r]),
                        fmaxf(acc[mt][2][r], acc[mt][3][r]));
#pragma unroll
        for (int o = 1; o < 16; o <<= 1) m = fmaxf(m, __shfl_xor(m, o, 64));
        float e[4], s = 0.f;
#pragma unroll
        for (int nt = 0; nt < 4; nt++) { e[nt] = __expf(acc[mt][nt][r] - m); s += e[nt]; }
#pragma unroll
        for (int o = 1; o < 16; o <<= 1) s += __shfl_xor(s, o, 64);
        const float inv = 1.f / s;
#pragma unroll
        for (int nt = 0; nt < 4; nt++) acc[mt][nt][r] = e[nt] * inv;
      }
  }

  // repack to bf16 in LDS (stride 136), then coalesced 16B stores
#pragma unroll
  for (int mt = 0; mt < 4; mt++)
#pragma unroll
    for (int nt = 0; nt < 4; nt++)
#pragma unroll
      for (int r = 0; r < 4; r++)
        sm.CsB[(wm * 64 + mt * 16 + quad * 4 + r) * 136 + wn * 64 + nt * 16 + row16] =
            f2bf(acc[mt][nt][r]);
  __syncthreads();
#pragma unroll
  for (int it = 0; it < 8; it++) {
    const int ch = tid + it * 256;        // 0..2047 = 128 rows x 16 chunks
    const int row = ch >> 4, ic = ch & 15;
    const uint4 val = *(const uint4*)&sm.CsB[row * 136 + ic * 8];
    *(uint4*)&C[(size_t)(bm + row) * DIM + bn + ic * 8] = val;
  }
}

// ---- fused tail: chunk_T -> prefix -> attn in ONE plain launch -------------
// grid 768 blocks (3/CU, exact capacity => co-resident => grid barrier safe).
// Blocks 0..255 own two (c,h,n) tiles.
// LDS: VT persistent (8448) + union{KT | Qs,Ks,Ts,Pb} (36864) = 45312 B.
__global__ __launch_bounds__(256, 3) void fused_tail(const ushort_t* __restrict__ qp,
                                                     const ushort_t* __restrict__ kp,
                                                     const ushort_t* __restrict__ vp,
                                                     float* __restrict__ cs,
                                                     ushort_t* __restrict__ csb,
                                                     float* __restrict__ out) {
  __shared__ unsigned int VT[64 * 33];
  __shared__ union TailU {
    unsigned int KT[64 * 33];
    struct { ushort_t Qs[64 * 72]; ushort_t Ks[64 * 72];
             ushort_t Ts[64 * 72]; ushort_t Pb[64 * 72]; } p3;
  } u;

  const int blk = blockIdx.x;
  const int tid = threadIdx.x;
  const int lane = tid & 63, wid = tid >> 6;
  const int row16 = lane & 15, quad = lane >> 4;

  int tiles[2];
  int ntiles = 0;
  tiles[ntiles++] = blk;
  if (blk + TGRID < NTILE) tiles[ntiles++] = blk + TGRID;

  // ---------------- phase 1: T_c per tile ----------------
  for (int i = 0; i < ntiles; i++) {
    const int t = tiles[i];
    const int c = t & 31, h = (t >> 5) & 15, n = t >> 9;
    const size_t gbase = ((size_t)(n * LSEQ + c * CS)) * DIM + h * DH;
    if (i) __syncthreads();                 // prior tile's LDS readers done
    transpose_tile(kp + gbase, u.KT, tid);
    transpose_tile(vp + gbase, VT, tid);
    __syncthreads();

    floatx4 acc[4] = {};
#pragma unroll
    for (int ks = 0; ks < 2; ks++) {
      const bf16x8 a = tfrag(VT, wid * 16 + row16, ks * 16 + quad * 4);
#pragma unroll
      for (int nt = 0; nt < 4; nt++) {
        const bf16x8 b = tfrag(u.KT, nt * 16 + row16, ks * 16 + quad * 4);
        acc[nt] = __builtin_amdgcn_mfma_f32_16x16x32_bf16(a, b, acc[nt], 0, 0, 0);
      }
    }
    float* outp = cs + ((size_t)((n * H + h) * NC + c)) * (DH * DH);
#pragma unroll
    for (int nt = 0; nt < 4; nt++)
#pragma unroll
      for (int r = 0; r < 4; r++)
        outp[(wid * 16 + quad * 4 + r) * DH + nt * 16 + row16] = acc[nt][r];
  }
  grid_sync_all();

  // ---------------- phase 2: exclusive prefix over chunks ----------------
  if (blk < NB * H * 16) {
    const int nh = blk >> 4;
    const int e  = (blk & 15) * 256 + tid;   // 0..4095
    const float* bf_ = cs + (size_t)nh * NC * (DH * DH) + e;
    ushort_t* bb = csb + (size_t)nh * NC * (DH * DH) + e;
    float run = 0.f;
#pragma unroll
    for (int c = 0; c < NC; c++) {
      const float cur = bf_[(size_t)c * (DH * DH)];
      bb[(size_t)c * (DH * DH)] = f2bf(run);
      run += cur;
    }
  }
  grid_sync_all();

  // ---------------- phase 3: out = Q Tpre^T + tril(Q K^T) V ----------------
  for (int i = 0; i < ntiles; i++) {
    const int t = tiles[i];
    const int c = t & 31, h = (t >> 5) & 15, n = t >> 9;
    const size_t gbase = ((size_t)(n * LSEQ + c * CS)) * DIM + h * DH;
    const size_t cbase = ((size_t)((n * H + h) * NC + c)) * (DH * DH);
    __syncthreads();                        // prior readers done before reuse

#pragma unroll
    for (int it = 0; it < 2; it++) {
      const int ch = tid + it * 256;        // 0..511
      const int row = ch >> 3, ic = ch & 7;
      *(uint4*)&u.p3.Qs[row * 72 + ic * 8] = *(const uint4*)&qp[gbase + (size_t)row * DIM + ic * 8];
      *(uint4*)&u.p3.Ks[row * 72 + ic * 8] = *(const uint4*)&kp[gbase + (size_t)row * DIM + ic * 8];
      *(uint4*)&u.p3.Ts[row * 72 + ic * 8] = *(const uint4*)&csb[cbase + (size_t)row * DH + ic * 8];
    }
    transpose_tile(vp + gbase, VT, tid);
    __syncthreads();

    const int t0 = wid * 16;
    floatx4 acc[4] = {};
    floatx4 pacc[4] = {};

#pragma unroll
    for (int ks = 0; ks < 2; ks++) {
      const bf16x8 aq = *(const bf16x8*)&u.p3.Qs[(t0 + row16) * 72 + ks * 32 + quad * 8];
#pragma unroll
      for (int nt = 0; nt < 4; nt++) {
        const bf16x8 bt = *(const bf16x8*)&u.p3.Ts[(nt * 16 + row16) * 72 + ks * 32 + quad * 8];
        acc[nt] = __builtin_amdgcn_mfma_f32_16x16x32_bf16(aq, bt, acc[nt], 0, 0, 0);
        const bf16x8 bk = *(const bf16x8*)&u.p3.Ks[(nt * 16 + row16) * 72 + ks * 32 + quad * 8];
        pacc[nt] = __builtin_amdgcn_mfma_f32_16x16x32_bf16(aq, bk, pacc[nt], 0, 0, 0);
      }
    }
#pragma unroll
    for (int nt = 0; nt < 4; nt++)
#pragma unroll
      for (int r = 0; r < 4; r++) {
        const int tt = t0 + quad * 4 + r, ss = nt * 16 + row16;
        u.p3.Pb[tt * 72 + ss] = f2bf((ss <= tt) ? pacc[nt][r] : 0.f);
      }
    __syncthreads();

#pragma unroll
    for (int ks = 0; ks < 2; ks++) {
      const bf16x8 ap = *(const bf16x8*)&u.p3.Pb[(t0 + row16) * 72 + ks * 32 + quad * 8];
#pragma unroll
      for (int nt = 0; nt < 4; nt++) {
        const bf16x8 bv = tfrag(VT, nt * 16 + row16, ks * 16 + quad * 4);
        acc[nt] = __builtin_amdgcn_mfma_f32_16x16x32_bf16(ap, bv, acc[nt], 0, 0, 0);
      }
    }

#pragma unroll
    for (int nt = 0; nt < 4; nt++)
#pragma unroll
      for (int r = 0; r < 4; r++)
        out[gbase + (size_t)(t0 + quad * 4 + r) * DIM + nt * 16 + row16] = acc[nt][r];
  }
}

extern "C" void kernel_launch(void* const* d_in, const int* in_sizes, int n_in,
                              void* d_out, int out_size, void* d_ws, size_t ws_size,
                              hipStream_t stream) {
  const float* query = (const float*)d_in[0];
  const float* key   = (const float*)d_in[1];
  const float* Wq    = (const float*)d_in[2];
  const float* Wk    = (const float*)d_in[3];
  const float* Wv    = (const float*)d_in[4];
  float* out = (float*)d_out;

  // d_ws: [qp 8MB bf16][kp 8MB][vp 8MB][cs 16MB f32][csb 8MB bf16] = 48MB
  // xbf (16MB) overlays cs; wbf (6MB) overlays d_out (dead until fused_tail)
  const size_t PM = (size_t)4 << 20;                 // 4M elements
  ushort_t* qp = (ushort_t*)d_ws;
  ushort_t* kp = qp + PM;
  ushort_t* vp = kp + PM;
  float*    cs = (float*)(vp + PM);
  ushort_t* csb = (ushort_t*)(cs + PM);
  ushort_t* xbf = (ushort_t*)cs;
  ushort_t* wbf = (ushort_t*)out;

  cast_all<<<dim3(512, 5), 256, 0, stream>>>(query, key, Wq, Wk, Wv, xbf, wbf);

  gemm_fused<<<dim3(768), 256, 0, stream>>>(xbf, wbf, qp, kp, vp);

  fused_tail<<<dim3(TGRID), 256, 0, stream>>>(qp, kp, vp, cs, csb, out);
}

// Round 5
// 156.275 us; speedup vs baseline: 2.6815x; 2.6815x over previous
//
#include <hip/hip_runtime.h>

// Causal linear attention (chunked scan), bf16 MFMA end-to-end.
// q = softmax(x Wq^T), k = softmax(x Wk^T), v = x Wv^T   (one fused MFMA GEMM)
// T_c = sum_{t in chunk} v_t^T (x) k_t  (= S_c^T)        (MFMA, pass A)
// Tpre = exclusive prefix of T_c over chunks (fp32 scan -> bf16)  (pass B)
// out = Q @ Tpre^T + tril(Q K^T) @ V                     (MFMA, pass C)

constexpr int DIM  = 1024;
constexpr int H    = 16;
constexpr int DH   = 64;
constexpr int LSEQ = 2048;
constexpr int NB   = 2;
constexpr int MTOK = NB * LSEQ;   // 4096 tokens
constexpr int CS   = 64;          // chunk size
constexpr int NC   = LSEQ / CS;   // 32 chunks

typedef __bf16 bf16x8 __attribute__((ext_vector_type(8)));
typedef float floatx4 __attribute__((ext_vector_type(4)));
typedef unsigned short ushort_t;

__device__ __forceinline__ ushort_t f2bf(float f) {
  unsigned int u = __float_as_uint(f);
  u += 0x7FFFu + ((u >> 16) & 1u);   // RTNE
  return (ushort_t)(u >> 16);
}

__device__ __forceinline__ void async16(void* lds, const void* g) {
  __builtin_amdgcn_global_load_lds(
      (const __attribute__((address_space(1))) unsigned int*)g,
      (__attribute__((address_space(3))) unsigned int*)lds, 16, 0, 0);
}

// read a bf16x8 fragment from a transposed stride-33-uint LDS array
__device__ __forceinline__ bf16x8 tfrag(const unsigned int* T, int row, int uoff) {
  union { bf16x8 v; unsigned int u[4]; } r;
  const unsigned int* p = T + row * 33 + uoff;
  r.u[0] = p[0]; r.u[1] = p[1]; r.u[2] = p[2]; r.u[3] = p[3];
  return r.v;
}

// transpose a 64x64 bf16 tile (global, row stride DIM) into stride-33-uint LDS
__device__ __forceinline__ void transpose_tile(const ushort_t* g, unsigned int* TT, int tid) {
  const int ic = tid & 7, tp = tid >> 3;       // tp 0..31, ic 0..7
  const ushort_t* r0 = g + (size_t)(2 * tp) * DIM + ic * 8;
  union { uint4 q; ushort_t u[8]; } a0, a1;
  a0.q = *(const uint4*)r0;
  a1.q = *(const uint4*)(r0 + DIM);
#pragma unroll
  for (int j = 0; j < 8; j++)
    TT[(8 * ic + j) * 33 + tp] = (unsigned int)a0.u[j] | ((unsigned int)a1.u[j] << 16);
}

// ------------- cast fp32 -> bf16 for query/key and the three weights --------
__global__ __launch_bounds__(256) void cast_all(const float* __restrict__ q,
                                                const float* __restrict__ k,
                                                const float* __restrict__ wq,
                                                const float* __restrict__ wk,
                                                const float* __restrict__ wv,
                                                ushort_t* __restrict__ xbf,
                                                ushort_t* __restrict__ wbf) {
  const int seg = blockIdx.y;
  const float* src;
  ushort_t* dst;
  int n4;
  if (seg == 0)      { src = q;  dst = xbf;                  n4 = (4 << 20) / 4; }
  else if (seg == 1) { src = k;  dst = xbf + (4 << 20);      n4 = (4 << 20) / 4; }
  else if (seg == 2) { src = wq; dst = wbf;                  n4 = (1 << 20) / 4; }
  else if (seg == 3) { src = wk; dst = wbf + (1 << 20);      n4 = (1 << 20) / 4; }
  else               { src = wv; dst = wbf + (2 << 20);      n4 = (1 << 20) / 4; }
  for (int i = blockIdx.x * 256 + threadIdx.x; i < n4; i += gridDim.x * 256) {
    const float4 f = ((const float4*)src)[i];
    ((ushort4*)dst)[i] = make_ushort4(f2bf(f.x), f2bf(f.y), f2bf(f.z), f2bf(f.w));
  }
}

// ----- fused bf16 MFMA GEMM NT: z in {0:q,1:k,2:v}, tile 256x256, BK=32 -----
// 512 threads = 8 waves in 2(M)x4(N); per-wave output 128x64 (8x4 MFMA frags).
// Register-double-buffered fragments: ds_read of K-step t+1 issues BEFORE the
// MFMAs of step t (overlap); LDS double-buffered (2x32KB), staged via
// global_load_lds with counted vmcnt(4) (next K-step's loads stay in flight).
// Bank-conflict-free via source+read XOR swizzle key (r ^ (r>>2)) & 3
// (8-lane service groups hit 8 distinct 16B bank-slots).
// Per-head softmax epilogue for z<2: each wave's 64-col span == one head.
struct Stage2 { ushort_t As[256 * 32]; ushort_t Ws[256 * 32]; };   // 32 KB
union SMemU { Stage2 st[2]; ushort_t CsB[64 * 264]; };             // 64 KB

__global__ __launch_bounds__(512, 2) void gemm_fused(const ushort_t* __restrict__ xbf,
                                                     const ushort_t* __restrict__ wbf,
                                                     ushort_t* __restrict__ qp,
                                                     ushort_t* __restrict__ kp,
                                                     ushort_t* __restrict__ vp) {
  __shared__ SMemU sm;
  const int tid = threadIdx.x;

  // XCD-aware decode: 192 blocks = 8 XCDs x 24. HW round-robins blockIdx%8
  // across XCDs; give each XCD a contiguous run of tiles (bn fastest).
  const int xcd   = blockIdx.x & 7;
  const int local = blockIdx.x >> 3;            // 0..23
  const int T     = xcd * 24 + local;           // 0..191
  const int z     = T >> 6;                     // 0..2
  const int rem   = T & 63;
  const int bm    = (rem >> 2) * 256;
  const int bn    = (rem & 3) * 256;

  const ushort_t* A = xbf + (z ? (size_t)(4 << 20) : 0);
  const ushort_t* W = wbf + (size_t)z * (1 << 20);
  ushort_t* C = (z == 0) ? qp : ((z == 1) ? kp : vp);

  const int lane  = tid & 63;
  const int wid   = tid >> 6;
  const int wr    = wid >> 2, wc = wid & 3;     // wave grid 2(M) x 4(N)
  const int row16 = lane & 15, quad = lane >> 4;

  floatx4 acc[8][4] = {};

  // ---- staging addresses (pre-swizzled global source, linear LDS dest) ----
  // A-tile 256x32 bf16 = 1024 16B-chunks; thread stages chunks tid and tid+512.
  // chunk c: row = c>>2, physical chunk p = c&3 holds logical chunk
  // p ^ key(row), key(r) = (r ^ (r>>2)) & 3.
  const int srow = tid >> 2;                                 // 0..127
  const int lc   = (tid & 3) ^ ((srow ^ (srow >> 2)) & 3);
  const ushort_t* pA0 = A + (size_t)(bm + srow) * DIM + lc * 8;
  const ushort_t* pA1 = A + (size_t)(bm + 128 + srow) * DIM + lc * 8;
  const ushort_t* pW0 = W + (size_t)(bn + srow) * DIM + lc * 8;
  const ushort_t* pW1 = W + (size_t)(bn + 128 + srow) * DIM + lc * 8;

#define STAGEB(B, kt)                                         \
  {                                                           \
    ushort_t* As_ = sm.st[B].As;                              \
    ushort_t* Ws_ = sm.st[B].Ws;                              \
    const int ko = (kt) * 32;                                 \
    async16(As_ + tid * 8,         pA0 + ko);                 \
    async16(As_ + (tid + 512) * 8, pA1 + ko);                 \
    async16(Ws_ + tid * 8,         pW0 + ko);                 \
    async16(Ws_ + (tid + 512) * 8, pW1 + ko);                 \
  }

  // ---- reader-side addresses (same swizzle key, per-thread constant) ------
  const int xq    = quad ^ ((row16 ^ (row16 >> 2)) & 3);
  const int aBase = (wr * 128 + row16) * 32 + xq * 8;   // + mt*512, mt 0..7
  const int bBase = (wc * 64 + row16) * 32 + xq * 8;    // + nt*512, nt 0..3

  bf16x8 aF0[8], bF0[4], aF1[8], bF1[4];

#define READB(B, AF, BF)                                                      \
  {                                                                           \
    _Pragma("unroll")                                                         \
    for (int mt = 0; mt < 8; mt++)                                            \
      AF[mt] = *(const bf16x8*)&sm.st[B].As[aBase + mt * 512];                \
    _Pragma("unroll")                                                         \
    for (int nt = 0; nt < 4; nt++)                                            \
      BF[nt] = *(const bf16x8*)&sm.st[B].Ws[bBase + nt * 512];                \
  }

#define MFMAB(AF, BF)                                                         \
  {                                                                           \
    _Pragma("unroll")                                                         \
    for (int mt = 0; mt < 8; mt++)                                            \
      _Pragma("unroll")                                                       \
      for (int nt = 0; nt < 4; nt++)                                          \
        acc[mt][nt] = __builtin_amdgcn_mfma_f32_16x16x32_bf16(                \
            AF[mt], BF[nt], acc[mt][nt], 0, 0, 0);                            \
  }

  // prologue: stage K-steps 0,1 (8 loads in flight), read step-0 fragments
  STAGEB(0, 0);
  STAGEB(1, 1);
  asm volatile("s_waitcnt vmcnt(4)" ::: "memory");   // own step-0 loads landed
  __builtin_amdgcn_s_barrier();                      // all waves' step-0 landed
  READB(0, aF0, bF0);

#pragma unroll
  for (int kt = 0; kt < 32; ++kt) {
    asm volatile("s_waitcnt lgkmcnt(0)" ::: "memory");  // step-kt frags in regs
    __builtin_amdgcn_s_barrier();                       // all waves done reading buf[kt&1]
    if (kt + 2 < 32) {
      if ((kt & 1) == 0) { STAGEB(0, kt + 2); } else { STAGEB(1, kt + 2); }
    }
    if (kt + 1 < 32) {
      if (kt + 2 < 32) { asm volatile("s_waitcnt vmcnt(4)" ::: "memory"); }
      else             { asm volatile("s_waitcnt vmcnt(0)" ::: "memory"); }
      __builtin_amdgcn_s_barrier();                     // buf[(kt+1)&1] staged for all
      if ((kt & 1) == 0) { READB(1, aF1, bF1); } else { READB(0, aF0, bF0); }
    }
    // MFMAs of step kt overlap the in-flight loads + issued ds_reads above
    if ((kt & 1) == 0) { MFMAB(aF0, bF0); } else { MFMAB(aF1, bF1); }
  }
#undef STAGEB
#undef READB
#undef MFMAB

  if (z < 2) {
    // in-register per-head softmax: row (mt,quad,r) spans nt regs x 16 lanes
#pragma unroll
    for (int mt = 0; mt < 8; mt++)
#pragma unroll
      for (int r = 0; r < 4; r++) {
        float m = fmaxf(fmaxf(acc[mt][0][r], acc[mt][1][r]),
                        fmaxf(acc[mt][2][r], acc[mt][3][r]));
#pragma unroll
        for (int o = 1; o < 16; o <<= 1) m = fmaxf(m, __shfl_xor(m, o, 64));
        float e[4], s = 0.f;
#pragma unroll
        for (int nt = 0; nt < 4; nt++) { e[nt] = __expf(acc[mt][nt][r] - m); s += e[nt]; }
#pragma unroll
        for (int o = 1; o < 16; o <<= 1) s += __shfl_xor(s, o, 64);
        const float inv = 1.f / s;
#pragma unroll
        for (int nt = 0; nt < 4; nt++) acc[mt][nt][r] = e[nt] * inv;
      }
  }

  // epilogue: 4 rounds of 64 rows; repack via LDS (stride 264), 16B stores
#pragma unroll
  for (int p = 0; p < 4; ++p) {
    __syncthreads();
    if (wr == (p >> 1)) {
      const int mh = (p & 1) * 4;
#pragma unroll
      for (int m4 = 0; m4 < 4; m4++)
#pragma unroll
        for (int nt = 0; nt < 4; nt++)
#pragma unroll
          for (int r = 0; r < 4; r++)
            sm.CsB[(m4 * 16 + quad * 4 + r) * 264 + wc * 64 + nt * 16 + row16] =
                f2bf(acc[mh + m4][nt][r]);
    }
    __syncthreads();
#pragma unroll
    for (int it = 0; it < 4; it++) {
      const int ch = tid + it * 512;        // 0..2047 = 64 rows x 32 chunks
      const int row = ch >> 5, ic = ch & 31;
      *(uint4*)&C[(size_t)(bm + p * 64 + row) * DIM + bn + ic * 8] =
          *(const uint4*)&sm.CsB[row * 264 + ic * 8];
    }
  }
}

// ------- pass A: T_c[j][i] = sum_t V[t][j] K[t][i]  (MFMA, fp32 out) --------
__global__ __launch_bounds__(256) void chunk_T(const ushort_t* __restrict__ kp,
                                               const ushort_t* __restrict__ vp,
                                               float* __restrict__ cs) {
  __shared__ unsigned int KT[64 * 33];
  __shared__ unsigned int VT[64 * 33];
  const int c = blockIdx.x, h = blockIdx.y, n = blockIdx.z;
  const int tid = threadIdx.x;
  const size_t gbase = ((size_t)(n * LSEQ + c * CS)) * DIM + h * DH;

  transpose_tile(kp + gbase, KT, tid);
  transpose_tile(vp + gbase, VT, tid);
  __syncthreads();

  const int lane = tid & 63, wid = tid >> 6;
  const int row16 = lane & 15, quad = lane >> 4;

  floatx4 acc[4] = {};
#pragma unroll
  for (int ks = 0; ks < 2; ks++) {
    const bf16x8 a = tfrag(VT, wid * 16 + row16, ks * 16 + quad * 4);
#pragma unroll
    for (int nt = 0; nt < 4; nt++) {
      const bf16x8 b = tfrag(KT, nt * 16 + row16, ks * 16 + quad * 4);
      acc[nt] = __builtin_amdgcn_mfma_f32_16x16x32_bf16(a, b, acc[nt], 0, 0, 0);
    }
  }
  float* outp = cs + ((size_t)((n * H + h) * NC + c)) * (DH * DH);
#pragma unroll
  for (int nt = 0; nt < 4; nt++)
#pragma unroll
    for (int r = 0; r < 4; r++)
      outp[(wid * 16 + quad * 4 + r) * DH + nt * 16 + row16] = acc[nt][r];
}

// ------- pass B: exclusive prefix over chunks (fp32 scan -> bf16 out) -------
__global__ __launch_bounds__(256) void prefix_chunks(const float* __restrict__ cs,
                                                     ushort_t* __restrict__ csb) {
  const int nh = blockIdx.x >> 4;
  const int e  = (blockIdx.x & 15) * 256 + threadIdx.x;   // 0..4095
  const float* bf_ = cs + (size_t)nh * NC * (DH * DH) + e;
  ushort_t* bb = csb + (size_t)nh * NC * (DH * DH) + e;
  float run = 0.f;
#pragma unroll
  for (int c = 0; c < NC; c++) {
    const float cur = bf_[(size_t)c * (DH * DH)];
    bb[(size_t)c * (DH * DH)] = f2bf(run);
    run += cur;
  }
}

// ---- pass C: out = Q @ Tpre^T + tril(Q K^T) @ V  (MFMA, fp32 out) ----------
__global__ __launch_bounds__(256) void attn_mfma(const ushort_t* __restrict__ qp,
                                                 const ushort_t* __restrict__ kp,
                                                 const ushort_t* __restrict__ vp,
                                                 const ushort_t* __restrict__ csb,
                                                 float* __restrict__ out) {
  __shared__ ushort_t Qs[64 * 72];
  __shared__ ushort_t Ks[64 * 72];
  __shared__ ushort_t Ts[64 * 72];
  __shared__ unsigned int VT[64 * 33];
  __shared__ ushort_t Pb[64 * 72];
  const int c = blockIdx.x, h = blockIdx.y, n = blockIdx.z;
  const int tid = threadIdx.x;
  const size_t gbase = ((size_t)(n * LSEQ + c * CS)) * DIM + h * DH;
  const size_t cbase = ((size_t)((n * H + h) * NC + c)) * (DH * DH);

#pragma unroll
  for (int it = 0; it < 2; it++) {
    const int ch = tid + it * 256;        // 0..511
    const int row = ch >> 3, ic = ch & 7;
    *(uint4*)&Qs[row * 72 + ic * 8] = *(const uint4*)&qp[gbase + (size_t)row * DIM + ic * 8];
    *(uint4*)&Ks[row * 72 + ic * 8] = *(const uint4*)&kp[gbase + (size_t)row * DIM + ic * 8];
    *(uint4*)&Ts[row * 72 + ic * 8] = *(const uint4*)&csb[cbase + (size_t)row * DH + ic * 8];
  }
  transpose_tile(vp + gbase, VT, tid);
  __syncthreads();

  const int lane = tid & 63, wid = tid >> 6;
  const int row16 = lane & 15, quad = lane >> 4;
  const int t0 = wid * 16;

  floatx4 acc[4] = {};
  floatx4 pacc[4] = {};

#pragma unroll
  for (int ks = 0; ks < 2; ks++) {
    const bf16x8 aq = *(const bf16x8*)&Qs[(t0 + row16) * 72 + ks * 32 + quad * 8];
#pragma unroll
    for (int nt = 0; nt < 4; nt++) {
      const bf16x8 bt = *(const bf16x8*)&Ts[(nt * 16 + row16) * 72 + ks * 32 + quad * 8];
      acc[nt] = __builtin_amdgcn_mfma_f32_16x16x32_bf16(aq, bt, acc[nt], 0, 0, 0);
      const bf16x8 bk = *(const bf16x8*)&Ks[(nt * 16 + row16) * 72 + ks * 32 + quad * 8];
      pacc[nt] = __builtin_amdgcn_mfma_f32_16x16x32_bf16(aq, bk, pacc[nt], 0, 0, 0);
    }
  }
#pragma unroll
  for (int nt = 0; nt < 4; nt++)
#pragma unroll
    for (int r = 0; r < 4; r++) {
      const int t = t0 + quad * 4 + r, s = nt * 16 + row16;
      Pb[t * 72 + s] = f2bf((s <= t) ? pacc[nt][r] : 0.f);
    }
  __syncthreads();

#pragma unroll
  for (int ks = 0; ks < 2; ks++) {
    const bf16x8 ap = *(const bf16x8*)&Pb[(t0 + row16) * 72 + ks * 32 + quad * 8];
#pragma unroll
    for (int nt = 0; nt < 4; nt++) {
      const bf16x8 bv = tfrag(VT, nt * 16 + row16, ks * 16 + quad * 4);
      acc[nt] = __builtin_amdgcn_mfma_f32_16x16x32_bf16(ap, bv, acc[nt], 0, 0, 0);
    }
  }

#pragma unroll
  for (int nt = 0; nt < 4; nt++)
#pragma unroll
    for (int r = 0; r < 4; r++)
      out[gbase + (size_t)(t0 + quad * 4 + r) * DIM + nt * 16 + row16] = acc[nt][r];
}

extern "C" void kernel_launch(void* const* d_in, const int* in_sizes, int n_in,
                              void* d_out, int out_size, void* d_ws, size_t ws_size,
                              hipStream_t stream) {
  const float* query = (const float*)d_in[0];
  const float* key   = (const float*)d_in[1];
  const float* Wq    = (const float*)d_in[2];
  const float* Wk    = (const float*)d_in[3];
  const float* Wv    = (const float*)d_in[4];
  float* out = (float*)d_out;

  // d_ws: [qp 8MB bf16][kp 8MB][vp 8MB][cs 16MB f32][csb 8MB bf16] = 48MB
  // xbf (16MB) overlays cs; wbf (6MB) overlays d_out (dead until attn_mfma)
  const size_t PM = (size_t)4 << 20;                 // 4M elements
  ushort_t* qp = (ushort_t*)d_ws;
  ushort_t* kp = qp + PM;
  ushort_t* vp = kp + PM;
  float*    cs = (float*)(vp + PM);
  ushort_t* csb = (ushort_t*)(cs + PM);
  ushort_t* xbf = (ushort_t*)cs;
  ushort_t* wbf = (ushort_t*)out;

  cast_all<<<dim3(512, 5), 256, 0, stream>>>(query, key, Wq, Wk, Wv, xbf, wbf);

  gemm_fused<<<dim3(192), 512, 0, stream>>>(xbf, wbf, qp, kp, vp);

  chunk_T<<<dim3(NC, H, NB), 256, 0, stream>>>(kp, vp, cs);
  prefix_chunks<<<dim3(NB * H * 16), 256, 0, stream>>>(cs, csb);
  attn_mfma<<<dim3(NC, H, NB), 256, 0, stream>>>(qp, kp, vp, csb, out);
}